// Round 5
// baseline (245.208 us; speedup 1.0000x reference)
//
#include <hip/hip_runtime.h>
#include <math.h>

// Round-5: node-count attack. Model from R0-R4: ~44us harness fill (fixed) +
// ~13us per graph node + ~40us of actual kernel work. 7 nodes -> 4 nodes:
//   memset -> k1(score/hist) -> k3all(k2+k3+k5 merged) -> k6nms(k6+k7 merged)
// using only validated barrier-free cross-block patterns:
//   - per-block redundant threshold recompute (replaces k2)
//   - retire-based tail election (validated R4-k3) for boundary + NMS
//   - guarded agent-scope flag spin (validated R3) for the 67 rank-blocks

#define NANCH 87296
#define NF 4256        // 1000*4 + 256 finalists
#define CAPD 128       // max neighbors per column
#define NITER 16       // 15 scan iterations + initial keep
#define BCAP 512       // boundary-bin buffer per level
#define EC 8192        // LDS edge cap (packed i<<16|j)
#define NBLK 341       // 256-anchor blocks; level boundaries are multiples of 256
#define BASE20 0xBD4CCu
#define NB20 9216      // padded to 1024 owners x 9 bins
#define BPT 9          // bins per owner
#define NTILE 2278     // 67*68/2 adjacency tiles
#define NRANK 67       // rank-blocks (67*64 = 4288 >= NF)

struct InPtrs {
    const float* cls[5];
    const float* reg[5];
    const float* loc;
};

// workspace layout
constexpr size_t SZ_HIST  = 5ull * NB20 * 4;            // 184,320
constexpr size_t OFF_HIST = 0;
constexpr size_t OFF_CNT  = OFF_HIST + SZ_HIST;
constexpr size_t OFF_CTR  = OFF_CNT + (size_t)NF * 4;   // [0]=fin,[1..5]=bCnt,[8]=k3elect,[9]=k6elect,[10]=flag
constexpr size_t ZERO_SZ  = OFF_CTR + 128;
constexpr size_t OFF_SBITS = ((ZERO_SZ + 255) / 256) * 256;
constexpr size_t OFF_CLSV  = OFF_SBITS + (size_t)NANCH * 4;
constexpr size_t OFF_PAR   = OFF_CLSV + (size_t)NANCH * 4;  // r[5] @ idx 8..12
constexpr size_t OFF_INVB  = OFF_PAR + 128;
constexpr size_t OFF_FINK  = ((OFF_INVB + (size_t)NBLK * 4 + 255) / 256) * 256;
constexpr size_t OFF_BBUF  = OFF_FINK + (size_t)NF * 8;
constexpr size_t OFF_SBOX  = OFF_BBUF + 5ull * BCAP * 8;
constexpr size_t OFF_SSC   = OFF_SBOX + (size_t)NF * 16;
constexpr size_t OFF_SCV   = OFF_SSC + (size_t)NF * 4;
constexpr size_t OFF_SAR   = OFF_SCV + (size_t)NF * 4;
constexpr size_t OFF_NBR   = OFF_SAR + (size_t)NF * 4;   // u32 entries

__device__ __forceinline__ void lvl_of(int a, int& lev, int& idx) {
    if (a < 65536)      { lev = 0; idx = a; }
    else if (a < 81920) { lev = 1; idx = a - 65536; }
    else if (a < 86016) { lev = 2; idx = a - 81920; }
    else if (a < 87040) { lev = 3; idx = a - 86016; }
    else                { lev = 4; idx = a - 87040; }
}

__device__ __forceinline__ unsigned int fkey(float f) {
    unsigned int u = __float_as_uint(f);
    return u ^ ((u & 0x80000000u) ? 0xFFFFFFFFu : 0x80000000u);
}
__device__ __forceinline__ float funkey(unsigned int k) {
    return __uint_as_float(k ^ ((k & 0x80000000u) ? 0x80000000u : 0xFFFFFFFFu));
}
__device__ __forceinline__ unsigned int bin20_addr(unsigned int v) {
    unsigned int owner = v / BPT;
    unsigned int i = v - owner * BPT;
    return (i << 10) | owner;
}
__device__ __forceinline__ unsigned int ald(const unsigned int* p) {
    return __hip_atomic_load((unsigned int*)p, __ATOMIC_RELAXED, __HIP_MEMORY_SCOPE_AGENT);
}
__device__ __forceinline__ void ast(unsigned int* p, unsigned int v) {
    __hip_atomic_store(p, v, __ATOMIC_RELAXED, __HIP_MEMORY_SCOPE_AGENT);
}
__device__ __forceinline__ void ast64(unsigned long long* p, unsigned long long v) {
    __hip_atomic_store(p, v, __ATOMIC_RELAXED, __HIP_MEMORY_SCOPE_AGENT);
}
__device__ __forceinline__ unsigned long long ald64(const unsigned long long* p) {
    return __hip_atomic_load((unsigned long long*)p, __ATOMIC_RELAXED, __HIP_MEMORY_SCOPE_AGENT);
}

// ---------------------------------------------------------------- K1
__global__ __launch_bounds__(1024) void k1_score(InPtrs P, unsigned int* hist,
        unsigned int* sbits, unsigned int* clsv, unsigned int* invBlk) {
    int t = threadIdx.x;
    int a = blockIdx.x * 256 + (t >> 2);
    int k = t & 3;
    int lev, idx; lvl_of(a, lev, idx);
    const float4* row = (const float4*)(P.cls[lev] + (size_t)idx * 80);
    float4 v[5];
    #pragma unroll
    for (int q = 0; q < 5; ++q) v[q] = row[q * 4 + k];
    float best = -INFINITY; int bi = 0;
    #pragma unroll
    for (int q = 0; q < 5; ++q) {
        int c0 = q * 16 + k * 4;
        if (v[q].x > best) { best = v[q].x; bi = c0 + 0; }
        if (v[q].y > best) { best = v[q].y; bi = c0 + 1; }
        if (v[q].z > best) { best = v[q].z; bi = c0 + 2; }
        if (v[q].w > best) { best = v[q].w; bi = c0 + 3; }
    }
    #pragma unroll
    for (int m = 1; m < 4; m <<= 1) {
        float ob = __shfl_xor(best, m, 64);
        int  obi = __shfl_xor(bi, m, 64);
        if (ob > best || (ob == best && obi < bi)) { best = ob; bi = obi; }
    }
    bool lead = (k == 0);
    unsigned int valid = 0;
    if (lead) {
        float score = 1.0f / (1.0f + expf(-best));
        valid = (score > 0.05f) ? 1u : 0u;
        float psm = valid ? score : -1.0f;
        unsigned int sb = fkey(psm);
        sbits[a] = sb;
        clsv[a] = (unsigned int)(bi + 1) | (valid << 31);
        if (valid) {
            unsigned int bin = (sb >> 12) - BASE20;
            atomicAdd(&hist[(size_t)lev * NB20 + bin20_addr(bin)], 1u);
        }
    }
    __shared__ unsigned int wv[16];
    unsigned long long mv = __ballot(lead && valid);
    int lane = t & 63, w = t >> 6;
    if (lane == 0) wv[w] = (unsigned int)__popcll(mv);
    __syncthreads();
    if (t == 0) {
        unsigned int s = 0;
        #pragma unroll
        for (int i = 0; i < 16; ++i) s += wv[i];
        invBlk[blockIdx.x] = 256u - s;
    }
}

// ---------------------------------------------------------------- K3all
// per-block threshold recompute (was k2) + compaction (k3) + tail boundary
// + 67 rank-blocks (was k5). 341 blocks x 256 threads, all co-resident.
__global__ __launch_bounds__(256) void k3_all(InPtrs P, const unsigned int* hist,
        const unsigned int* sbits, const unsigned int* clsv,
        const unsigned int* invBlk, unsigned int* params, unsigned int* ctrs,
        unsigned long long* finKeys, unsigned long long* bBuf,
        float4* sBox, float* sScore, unsigned int* sCV, float* sArea) {
    int blk = blockIdx.x;
    int t = threadIdx.x;
    int lane = t & 63, wid = t >> 6;

    int lev, segStart;
    if (blk < 256)      { lev = 0; segStart = 0; }
    else if (blk < 320) { lev = 1; segStart = 256; }
    else if (blk < 336) { lev = 2; segStart = 320; }
    else if (blk < 340) { lev = 3; segStart = 336; }
    else                { lev = 4; segStart = 340; }
    unsigned int K = (lev == 4) ? 256u : 1000u;
    const unsigned int* h = hist + (size_t)lev * NB20;

    __shared__ union {
        struct { unsigned int osum[1024]; } pre;                 // 4 KB
        struct { unsigned long long kb[BCAP]; } tl;              // 4 KB
        struct { unsigned long long keys[NF]; unsigned int rnk[64]; } rk;  // 34.3 KB
    } u;
    __shared__ unsigned int red[4];
    __shared__ unsigned int sBs, sR, sRneg;
    __shared__ unsigned int wInv[4], wFin[4], wB[4];
    __shared__ unsigned int baseFin, baseB, myRank, posS;

    // ---- prologue: level threshold (k2 math, 256 threads x 4 owners) ----
    unsigned int s4[4];
    #pragma unroll
    for (int c = 0; c < 4; ++c) {
        int ow = t + (c << 8);
        unsigned int s = 0;
        #pragma unroll
        for (int i = 0; i < BPT; ++i) s += h[(i << 10) | ow];
        s4[c] = s; u.pre.osum[ow] = s;
    }
    __syncthreads();
    for (int off = 1; off < 1024; off <<= 1) {
        unsigned int v[4], a2[4];
        #pragma unroll
        for (int c = 0; c < 4; ++c) {
            int idx = t + (c << 8);
            v[c] = u.pre.osum[idx];
            a2[c] = (idx + off < 1024) ? u.pre.osum[idx + off] : 0u;
        }
        __syncthreads();
        #pragma unroll
        for (int c = 0; c < 4; ++c) { int idx = t + (c << 8); u.pre.osum[idx] = v[c] + a2[c]; }
        __syncthreads();
    }
    unsigned int totValid = u.pre.osum[0];
    if (totValid >= K) {
        #pragma unroll
        for (int c = 0; c < 4; ++c) {
            int ow = t + (c << 8);
            unsigned int osuf = u.pre.osum[ow];
            unsigned int excl = osuf - s4[c];
            if (excl < K && osuf >= K) {            // unique crossing owner
                unsigned int cum = excl;
                for (int i = BPT - 1; i >= 0; --i) {
                    unsigned int cc = h[(i << 10) | ow];
                    if (cum + cc >= K) { sBs = (unsigned int)(ow * BPT + i);
                                         sR = K - cum; sRneg = 0; break; }
                    cum += cc;
                }
            }
        }
    } else if (t == 0) { sBs = 0; sR = 0; sRneg = K - totValid; }
    // ---- invOff for this block (was k2 block-5) ----
    unsigned int lsum = 0;
    for (int i = segStart + t; i < blk; i += 256) lsum += invBlk[i];
    #pragma unroll
    for (int m = 1; m < 64; m <<= 1) lsum += __shfl_xor(lsum, m, 64);
    if (lane == 0) red[wid] = lsum;
    __syncthreads();
    unsigned int invOffBlk = red[0] + red[1] + red[2] + red[3];
    unsigned int Bs = sBs, rNeg = sRneg;
    if (blk == segStart && t == 0) ast(&params[8 + lev], sR);  // for tail

    // ---- compaction (k3 body) ----
    int a = blk * 256 + t;
    unsigned int sb = sbits[a];
    unsigned int cv = clsv[a];
    unsigned int bin = (sb >> 12) - BASE20;
    unsigned int valid = cv >> 31;
    unsigned long long lt = (1ull << lane) - 1ull;
    unsigned long long mInv = __ballot(valid == 0u);
    if (lane == 0) wInv[wid] = (unsigned int)__popcll(mInv);
    __syncthreads();
    unsigned int invRank = invOffBlk + (unsigned int)__popcll(mInv & lt);
    for (int i = 0; i < wid; ++i) invRank += wInv[i];
    bool isFin, isB;
    if (valid) { isFin = (bin > Bs); isB = (bin == Bs); }
    else       { isFin = (rNeg > 0) && (invRank < rNeg); isB = false; }
    unsigned long long mFin = __ballot(isFin);
    unsigned long long mB   = __ballot(isB);
    if (lane == 0) { wFin[wid] = (unsigned int)__popcll(mFin);
                     wB[wid]   = (unsigned int)__popcll(mB); }
    __syncthreads();
    if (t == 0) {
        unsigned int tf = wFin[0] + wFin[1] + wFin[2] + wFin[3];
        unsigned int tb = wB[0] + wB[1] + wB[2] + wB[3];
        baseFin = tf ? atomicAdd(&ctrs[0], tf) : 0u;
        baseB   = tb ? atomicAdd(&ctrs[1 + lev], tb) : 0u;
    }
    __syncthreads();
    if (isFin || isB) {
        int lidx = a - segStart * 256;
        unsigned int composite = ((unsigned int)lev << 16) | (unsigned int)lidx;
        unsigned int inv = (~composite) & 0x7FFFFu;
        unsigned int low = (inv << 13) | (valid << 7) | (cv & 0x7Fu);
        unsigned long long key = ((unsigned long long)sb << 32) | low;
        if (isFin) {
            unsigned int p = baseFin + (unsigned int)__popcll(mFin & lt);
            for (int i = 0; i < wid; ++i) p += wFin[i];
            if (p < NF) ast64(&finKeys[p], key);
        } else {
            unsigned int p = baseB + (unsigned int)__popcll(mB & lt);
            for (int i = 0; i < wid; ++i) p += wB[i];
            if (p < BCAP) ast64(&bBuf[(size_t)lev * BCAP + p], key);
        }
    }

    // ---- election (retire-based, validated R4) ----
    __syncthreads();
    if (t == 0) {
        asm volatile("s_waitcnt vmcnt(0)" ::: "memory");
        myRank = __hip_atomic_fetch_add(&ctrs[8], 1u,
                     __ATOMIC_RELAXED, __HIP_MEMORY_SCOPE_AGENT);
    }
    __syncthreads();
    unsigned int rk_ = myRank;
    if (rk_ < (unsigned int)(NBLK - 1 - NRANK)) return;   // ranks 0..272 exit

    if (rk_ == (unsigned int)(NBLK - 1)) {
        // ---- tail: boundary resolution ----
        unsigned int fc = ald(&ctrs[0]);
        if (fc > NF) fc = NF;
        if (t == 0) posS = fc;
        __syncthreads();
        for (int blev = 0; blev < 5; ++blev) {
            unsigned int bc = ald(&ctrs[1 + blev]);
            int n = (bc > BCAP) ? BCAP : (int)bc;
            int r = (int)ald(&params[8 + blev]);
            if (r > n) r = n;
            if (r > 0) {
                for (int i = t; i < n; i += 256)
                    u.tl.kb[i] = ald64(&bBuf[(size_t)blev * BCAP + i]);
                __syncthreads();
                for (int i = t; i < n; i += 256) {
                    unsigned long long my = u.tl.kb[i];
                    unsigned int c = 0;
                    for (int j = 0; j < n; ++j) c += (u.tl.kb[j] > my) ? 1u : 0u;
                    if (c < (unsigned int)r) {
                        unsigned int p = atomicAdd(&posS, 1u);
                        if (p < NF) ast64(&finKeys[p], my);
                    }
                }
                __syncthreads();
            }
        }
        __syncthreads();
        for (int i = (int)posS + t; i < NF; i += 256)
            ast64(&finKeys[i], (unsigned long long)i);
        __syncthreads();
        if (t == 0) {
            asm volatile("s_waitcnt vmcnt(0)" ::: "memory");
            ast(&ctrs[10], 1u);                    // release rank-blocks
        }
        return;
    }

    // ---- rank-block (was k5): guarded spin, then rank 64 finalists ----
    if (t == 0) {
        int g = 0;
        while (ald(&ctrs[10]) == 0u && g < 200000) { __builtin_amdgcn_s_sleep(8); ++g; }
    }
    __syncthreads();
    int rb = (int)rk_ - (NBLK - 1 - NRANK);        // 0..66
    for (int i = t; i < NF; i += 256) u.rk.keys[i] = ald64(&finKeys[i]);
    if (t < 64) u.rk.rnk[t] = 0;
    __syncthreads();
    int lf = t & 63;
    int seg = t >> 6;                              // 4 segments of 1064 keys
    int f = rb * 64 + lf;
    unsigned long long my = (f < NF) ? u.rk.keys[f] : 0ull;
    if (f < NF) {
        unsigned int c = 0;
        const unsigned long long* kp = u.rk.keys + seg * 1064;
        #pragma unroll 8
        for (int i = 0; i < 1064; ++i) c += (kp[i] > my) ? 1u : 0u;
        atomicAdd(&u.rk.rnk[lf], c);
    }
    __syncthreads();
    if (seg == 0 && f < NF) {
        unsigned int r = u.rk.rnk[lf];
        unsigned int sbv = (unsigned int)(my >> 32);
        unsigned int low = (unsigned int)my;
        unsigned int composite = (~(low >> 13)) & 0x7FFFFu;
        int lev2 = composite >> 16;
        int idx = composite & 0xFFFF;
        float4 b = ((const float4*)P.reg[lev2])[idx];
        float vy1 = P.loc[0], vx1 = P.loc[1], vy2 = P.loc[2], vx2 = P.loc[3];
        float y1 = fmaxf(b.x, vy1), x1 = fmaxf(b.y, vx1);
        float y2 = fminf(b.z, vy2), x2 = fminf(b.w, vx2);
        float area = __fmul_rn(fmaxf(y2 - y1, 0.0f), fmaxf(x2 - x1, 0.0f));
        unsigned int valid2 = (low >> 7) & 1u;
        sBox[r] = make_float4(y1, x1, y2, x2);
        sScore[r] = valid2 ? funkey(sbv) : 0.0f;
        sCV[r] = (low & 0x7Fu) | (valid2 << 31);
        sArea[r] = area;
    }
}

// ---------------------------------------------------------------- K6+NMS
// adjacency tiles + retire-based tail election; last block runs NMS + emit.
__global__ __launch_bounds__(256) void k6_nms(InPtrs P, const float4* sBox,
        const float* sArea, const float* sScore, const unsigned int* sCV,
        unsigned int* cnt, unsigned int* nbr, unsigned int* ctrs,
        float* __restrict__ out) {
    __shared__ float4 cb[64]; __shared__ float ca[64];
    __shared__ float4 rbx[64]; __shared__ float ra[64];
    __shared__ unsigned int edges[EC];                 // 32 KB
    __shared__ __align__(4) unsigned char bufA[NF];
    __shared__ __align__(4) unsigned char bufB[NF];
    __shared__ unsigned int wsum[4];
    __shared__ float ploc[6];
    __shared__ unsigned int chg, rk2;
    int t = threadIdx.x;
    int lane = t & 63, wid = t >> 6;

    {   // ---- adjacency (k6 body, no early returns) ----
        int L = blockIdx.x;
        float fr = sqrtf(8.0f * (float)L + 1.0f);
        int jt = (int)((fr - 1.0f) * 0.5f);
        while ((jt + 1) * (jt + 2) / 2 <= L) jt++;
        while (jt * (jt + 1) / 2 > L) jt--;
        int it = L - jt * (jt + 1) / 2;
        if (t < 64) {
            int j = jt * 64 + t;
            if (j < NF) { cb[t] = sBox[j]; ca[t] = sArea[j]; }
            int i = it * 64 + t;
            if (i < NF) { rbx[t] = sBox[i]; ra[t] = sArea[i]; }
        }
        __syncthreads();
        int lj = t & 63;
        int j = jt * 64 + lj;
        if (j < NF) {
            float4 B = cb[lj]; float ab = ca[lj];
            for (int li = (t >> 6); li < 64; li += 4) {
                int i = it * 64 + li;
                if (i >= j) continue;
                float4 A = rbx[li]; float aa = ra[li];
                float iy1 = fmaxf(A.x, B.x), ix1 = fmaxf(A.y, B.y);
                float iy2 = fminf(A.z, B.z), ix2 = fminf(A.w, B.w);
                float ih = fmaxf(iy2 - iy1, 0.0f), iw = fmaxf(ix2 - ix1, 0.0f);
                float inter = __fmul_rn(ih, iw);
                float uni = __fsub_rn(__fadd_rn(aa, ab), inter);
                float iou = __fdiv_rn(inter, fmaxf(uni, 1e-9f));
                if (iou > 0.5f) {
                    unsigned int p = atomicAdd(&cnt[j], 1u);
                    if (p < CAPD) ast(&nbr[(size_t)j * CAPD + p], (unsigned int)i);
                }
            }
        }
    }
    // ---- election ----
    __syncthreads();
    if (t == 0) {
        asm volatile("s_waitcnt vmcnt(0)" ::: "memory");
        rk2 = __hip_atomic_fetch_add(&ctrs[9], 1u,
                  __ATOMIC_RELAXED, __HIP_MEMORY_SCOPE_AGENT);
    }
    __syncthreads();
    if (rk2 != (unsigned int)(NTILE - 1)) return;

    // ---- NMS + emit (was k7), 256 threads, CH=17 ----
    const int CH = 17;
    if (t < 6) ploc[t] = P.loc[t];
    if (t == 0) chg = 0;
    unsigned int dq[CH];
    unsigned int s = 0;
    #pragma unroll
    for (int q = 0; q < CH; ++q) {
        int j = t * CH + q;
        unsigned int d = 0;
        if (j < NF) { d = ald(&cnt[j]); if (d > CAPD) d = CAPD; }
        dq[q] = d; s += d;
    }
    unsigned int sc = s;
    #pragma unroll
    for (int o = 1; o < 64; o <<= 1) {
        unsigned int n = __shfl_up(sc, o, 64);
        if (lane >= o) sc += n;
    }
    if (lane == 63) wsum[wid] = sc;
    for (int i = t; i < 1064; i += 256) ((unsigned int*)bufA)[i] = 0x01010101u;
    __syncthreads();
    unsigned int wbase = 0, tot = 0;
    #pragma unroll
    for (int i = 0; i < 4; ++i) {
        unsigned int v = wsum[i];
        if (i < wid) wbase += v;
        tot += v;
    }
    unsigned int E = tot;
    bool useLds = (E <= (unsigned int)EC);
    if (useLds) {
        unsigned int base = wbase + sc - s;
        #pragma unroll
        for (int q = 0; q < CH; ++q) {
            int j = t * CH + q;
            if (j < NF) {
                unsigned int d = dq[q];
                const unsigned int* nl = nbr + (size_t)j * CAPD;
                for (unsigned int e = 0; e < d; ++e)
                    edges[base + e] = (ald(&nl[e]) << 16) | (unsigned int)j;
                base += d;
            }
        }
    }
    __syncthreads();
    unsigned char* cur = bufA; unsigned char* nxt = bufB;
    for (int itr = 0; itr < NITER; ++itr) {
        for (int i = t; i < 1064; i += 256) ((unsigned int*)nxt)[i] = 0x01010101u;
        __syncthreads();
        if (useLds) {
            for (int e = t; e < (int)E; e += 256) {
                unsigned int pk = edges[e];
                if (cur[pk >> 16]) nxt[pk & 0xFFFFu] = 0;
            }
        } else {
            for (int j = t; j < NF; j += 256) {
                unsigned int d = ald(&cnt[j]); if (d > CAPD) d = CAPD;
                const unsigned int* nl = nbr + (size_t)j * CAPD;
                unsigned int hit = 0;
                for (unsigned int e = 0; e < d; ++e)
                    hit |= (unsigned int)cur[ald(&nl[e])];
                if (hit) nxt[j] = 0;
            }
        }
        __syncthreads();
        for (int i = t; i < 1064; i += 256)
            if (((unsigned int*)nxt)[i] != ((unsigned int*)cur)[i]) chg = 1;
        __syncthreads();
        unsigned int done = (chg == 0u);
        unsigned char* tm = cur; cur = nxt; nxt = tm;
        __syncthreads();
        if (t == 0) chg = 0;
        if (done) break;
    }
    // final keep & emit
    int base2 = t * CH;
    unsigned char kf[CH];
    unsigned int sum = 0;
    #pragma unroll
    for (int q = 0; q < CH; ++q) {
        int j = base2 + q;
        unsigned char v = 0;
        if (j < NF) v = cur[j] & (unsigned char)(sCV[j] >> 31);
        kf[q] = v; sum += v;
    }
    unsigned int sc2 = sum;
    #pragma unroll
    for (int o = 1; o < 64; o <<= 1) {
        unsigned int n = __shfl_up(sc2, o, 64);
        if (lane >= o) sc2 += n;
    }
    if (lane == 63) wsum[wid] = sc2;
    __syncthreads();
    unsigned int wbase2 = 0, keptTot = 0;
    #pragma unroll
    for (int i = 0; i < 4; ++i) {
        unsigned int v = wsum[i];
        if (i < wid) wbase2 += v;
        keptTot += v;
    }
    unsigned int run = wbase2 + sc2 - sum;
    float vy1 = ploc[0], vx1 = ploc[1], vy2 = ploc[2], vx2 = ploc[3];
    float sy = ploc[4] / fmaxf(vy2 - vy1, 1e-6f);
    float sx = ploc[5] / fmaxf(vx2 - vx1, 1e-6f);
    #pragma unroll
    for (int q = 0; q < CH; ++q) {
        int j = base2 + q;
        if (j >= NF) break;
        unsigned int slot = 0xFFFFFFFFu;
        float scv = 0.0f;
        if (kf[q]) {
            if (run < 100u) { slot = run; scv = sScore[j]; }
            run++;
        } else if (keptTot < 100u) {
            unsigned int nk = (unsigned int)j - run;
            unsigned int s2 = keptTot + nk;
            if (s2 < 100u) { slot = s2; scv = 0.0f; }
        }
        if (slot < 100u) {
            float4 b = sBox[j];
            out[slot * 4 + 0] = (b.x - vy1) * sy;
            out[slot * 4 + 1] = (b.y - vx1) * sx;
            out[slot * 4 + 2] = (b.z - vy1) * sy;
            out[slot * 4 + 3] = (b.w - vx1) * sx;
            out[400 + slot] = (float)(sCV[j] & 0x7Fu);
            out[500 + slot] = scv;
        }
    }
}

extern "C" void kernel_launch(void* const* d_in, const int* in_sizes, int n_in,
                              void* d_out, int out_size, void* d_ws, size_t ws_size,
                              hipStream_t stream) {
    (void)n_in; (void)out_size; (void)ws_size;
    InPtrs P;
    bool inter = (in_sizes[1] == 65536 * 4);
    for (int s = 0; s < 5; ++s) {
        P.cls[s] = (const float*)d_in[inter ? 2 * s : s];
        P.reg[s] = (const float*)d_in[inter ? 2 * s + 1 : 5 + s];
    }
    P.loc = (const float*)d_in[10];

    char* w = (char*)d_ws;
    unsigned int* hist   = (unsigned int*)(w + OFF_HIST);
    unsigned int* cnt    = (unsigned int*)(w + OFF_CNT);
    unsigned int* ctrs   = (unsigned int*)(w + OFF_CTR);
    unsigned int* sbits  = (unsigned int*)(w + OFF_SBITS);
    unsigned int* clsv   = (unsigned int*)(w + OFF_CLSV);
    unsigned int* params = (unsigned int*)(w + OFF_PAR);
    unsigned int* invBlk = (unsigned int*)(w + OFF_INVB);
    unsigned long long* finKeys = (unsigned long long*)(w + OFF_FINK);
    unsigned long long* bBuf    = (unsigned long long*)(w + OFF_BBUF);
    float4* sBox  = (float4*)(w + OFF_SBOX);
    float* sScore = (float*)(w + OFF_SSC);
    unsigned int* sCV = (unsigned int*)(w + OFF_SCV);
    float* sArea  = (float*)(w + OFF_SAR);
    unsigned int* nbr = (unsigned int*)(w + OFF_NBR);

    hipMemsetAsync(d_ws, 0, ZERO_SZ, stream);
    k1_score<<<NBLK, 1024, 0, stream>>>(P, hist, sbits, clsv, invBlk);
    k3_all<<<NBLK, 256, 0, stream>>>(P, hist, sbits, clsv, invBlk, params, ctrs,
                                     finKeys, bBuf, sBox, sScore, sCV, sArea);
    k6_nms<<<NTILE, 256, 0, stream>>>(P, sBox, sArea, sScore, sCV, cnt, nbr,
                                      ctrs, (float*)d_out);
}

// Round 6
// 192.004 us; speedup vs baseline: 1.2771x; 1.2771x over previous
//
#include <hip/hip_runtime.h>
#include <math.h>

// Round-6: R4 structure (known 173us) minus 2 nodes. Lesson from R5: merge is
// only profitable when the merged tail keeps WIDE geometry and CACHED loads --
// k7's NMS (serial, needs 1024 thr + cached nbr) stays a separate kernel.
// Merges kept:
//  - k2 -> k1 tail (1024-thr tail block, parallel 5-level scan)  [retire-elect]
//  - k5 -> k3 (67 rank-blocks via election ranks + boundary tail) [flag-spin]
// 5 nodes: memset, k1(+k2), k3(+k5), k6, k7.

#define NANCH 87296
#define NF 4256        // 1000*4 + 256 finalists
#define CAPD 128       // max neighbors per column
#define NITER 16       // 15 scan iterations + initial keep
#define BCAP 512       // boundary-bin buffer per level
#define EC 8192        // LDS edge cap (packed i<<16|j)
#define NBLK 341       // 256-anchor blocks; level boundaries are multiples of 256
#define BASE20 0xBD4CCu
#define NB20 9216      // padded to 1024 owners x 9 bins
#define BPT 9          // bins per owner
#define NRANK 67       // rank-blocks (67*64 = 4288 >= NF)

struct InPtrs {
    const float* cls[5];
    const float* reg[5];
    const float* loc;
};

// workspace layout
constexpr size_t SZ_HIST  = 5ull * NB20 * 4;            // 184,320
constexpr size_t OFF_HIST = 0;
constexpr size_t OFF_CNT  = OFF_HIST + SZ_HIST;
constexpr size_t OFF_CTR  = OFF_CNT + (size_t)NF * 4;   // [0]=fin,[1..5]=bCnt,[8]=k3elect,[10]=k5flag,[11]=k1elect
constexpr size_t ZERO_SZ  = OFF_CTR + 128;
constexpr size_t OFF_SBITS = ((ZERO_SZ + 255) / 256) * 256;
constexpr size_t OFF_CLSV  = OFF_SBITS + (size_t)NANCH * 4;
constexpr size_t OFF_PAR   = OFF_CLSV + (size_t)NANCH * 4;  // B*[5]@0,r*[5]@8,rNeg[5]@16
constexpr size_t OFF_INVB  = OFF_PAR + 128;
constexpr size_t OFF_INVO  = OFF_INVB + (size_t)NBLK * 4;
constexpr size_t OFF_FINK  = ((OFF_INVO + (size_t)NBLK * 4 + 255) / 256) * 256;
constexpr size_t OFF_BBUF  = OFF_FINK + (size_t)NF * 8;
constexpr size_t OFF_SBOX  = OFF_BBUF + 5ull * BCAP * 8;
constexpr size_t OFF_SSC   = OFF_SBOX + (size_t)NF * 16;
constexpr size_t OFF_SCV   = OFF_SSC + (size_t)NF * 4;
constexpr size_t OFF_SAR   = OFF_SCV + (size_t)NF * 4;
constexpr size_t OFF_NBR   = OFF_SAR + (size_t)NF * 4;

__device__ __forceinline__ void lvl_of(int a, int& lev, int& idx) {
    if (a < 65536)      { lev = 0; idx = a; }
    else if (a < 81920) { lev = 1; idx = a - 65536; }
    else if (a < 86016) { lev = 2; idx = a - 81920; }
    else if (a < 87040) { lev = 3; idx = a - 86016; }
    else                { lev = 4; idx = a - 87040; }
}

__device__ __forceinline__ unsigned int fkey(float f) {
    unsigned int u = __float_as_uint(f);
    return u ^ ((u & 0x80000000u) ? 0xFFFFFFFFu : 0x80000000u);
}
__device__ __forceinline__ float funkey(unsigned int k) {
    return __uint_as_float(k ^ ((k & 0x80000000u) ? 0x80000000u : 0xFFFFFFFFu));
}
__device__ __forceinline__ unsigned int bin20_addr(unsigned int v) {
    unsigned int owner = v / BPT;
    unsigned int i = v - owner * BPT;
    return (i << 10) | owner;
}
__device__ __forceinline__ unsigned int ald(const unsigned int* p) {
    return __hip_atomic_load((unsigned int*)p, __ATOMIC_RELAXED, __HIP_MEMORY_SCOPE_AGENT);
}
__device__ __forceinline__ void ast(unsigned int* p, unsigned int v) {
    __hip_atomic_store(p, v, __ATOMIC_RELAXED, __HIP_MEMORY_SCOPE_AGENT);
}
__device__ __forceinline__ void ast64(unsigned long long* p, unsigned long long v) {
    __hip_atomic_store(p, v, __ATOMIC_RELAXED, __HIP_MEMORY_SCOPE_AGENT);
}
__device__ __forceinline__ unsigned long long ald64(const unsigned long long* p) {
    return __hip_atomic_load((unsigned long long*)p, __ATOMIC_RELAXED, __HIP_MEMORY_SCOPE_AGENT);
}

// ---------------------------------------------------------------- K1 (+K2)
__global__ __launch_bounds__(1024) void k1_score(InPtrs P, unsigned int* hist,
        unsigned int* sbits, unsigned int* clsv, unsigned int* invBlk,
        unsigned int* params, unsigned int* invOff, unsigned int* ctrs) {
    int t = threadIdx.x;
    int a = blockIdx.x * 256 + (t >> 2);
    int k = t & 3;
    int lev, idx; lvl_of(a, lev, idx);
    const float4* row = (const float4*)(P.cls[lev] + (size_t)idx * 80);
    float4 v[5];
    #pragma unroll
    for (int q = 0; q < 5; ++q) v[q] = row[q * 4 + k];
    float best = -INFINITY; int bi = 0;
    #pragma unroll
    for (int q = 0; q < 5; ++q) {
        int c0 = q * 16 + k * 4;
        if (v[q].x > best) { best = v[q].x; bi = c0 + 0; }
        if (v[q].y > best) { best = v[q].y; bi = c0 + 1; }
        if (v[q].z > best) { best = v[q].z; bi = c0 + 2; }
        if (v[q].w > best) { best = v[q].w; bi = c0 + 3; }
    }
    #pragma unroll
    for (int m = 1; m < 4; m <<= 1) {
        float ob = __shfl_xor(best, m, 64);
        int  obi = __shfl_xor(bi, m, 64);
        if (ob > best || (ob == best && obi < bi)) { best = ob; bi = obi; }
    }
    bool lead = (k == 0);
    unsigned int valid = 0;
    if (lead) {
        float score = 1.0f / (1.0f + expf(-best));
        valid = (score > 0.05f) ? 1u : 0u;
        float psm = valid ? score : -1.0f;
        unsigned int sb = fkey(psm);
        sbits[a] = sb;
        clsv[a] = (unsigned int)(bi + 1) | (valid << 31);
        if (valid) {
            unsigned int bin = (sb >> 12) - BASE20;
            atomicAdd(&hist[(size_t)lev * NB20 + bin20_addr(bin)], 1u);
        }
    }
    __shared__ unsigned int wv[16];
    __shared__ unsigned int isLast;
    unsigned long long mv = __ballot(lead && valid);
    int lane = t & 63, w = t >> 6;
    if (lane == 0) wv[w] = (unsigned int)__popcll(mv);
    __syncthreads();
    if (t == 0) {
        unsigned int s = 0;
        #pragma unroll
        for (int i = 0; i < 16; ++i) s += wv[i];
        ast(&invBlk[blockIdx.x], 256u - s);     // agent store: tail alds it
    }
    // ---- retire election (validated R4) ----
    __syncthreads();
    if (t == 0) {
        asm volatile("s_waitcnt vmcnt(0)" ::: "memory");
        unsigned int r = __hip_atomic_fetch_add(&ctrs[11], 1u,
                             __ATOMIC_RELAXED, __HIP_MEMORY_SCOPE_AGENT);
        isLast = (r == (unsigned int)(NBLK - 1)) ? 1u : 0u;
    }
    __syncthreads();
    if (!isLast) return;

    // ---- tail: k2 work, 1024 threads, 5 levels in parallel ----
    __shared__ unsigned int sc[5 * 1024];       // 20 KB
    unsigned int s4[5];
    #pragma unroll
    for (int lv = 0; lv < 5; ++lv) {
        const unsigned int* h = hist + (size_t)lv * NB20;
        unsigned int s = 0;
        #pragma unroll
        for (int i = 0; i < BPT; ++i) s += ald(&h[(i << 10) | t]);
        s4[lv] = s; sc[lv * 1024 + t] = s;
    }
    __syncthreads();
    for (int off = 1; off < 1024; off <<= 1) {
        unsigned int vv[5], a2[5];
        #pragma unroll
        for (int lv = 0; lv < 5; ++lv) {
            vv[lv] = sc[lv * 1024 + t];
            a2[lv] = (t + off < 1024) ? sc[lv * 1024 + t + off] : 0u;
        }
        __syncthreads();
        #pragma unroll
        for (int lv = 0; lv < 5; ++lv) sc[lv * 1024 + t] = vv[lv] + a2[lv];
        __syncthreads();
    }
    #pragma unroll
    for (int lv = 0; lv < 5; ++lv) {
        unsigned int K = (lv == 4) ? 256u : 1000u;
        unsigned int tot = sc[lv * 1024];
        if (tot >= K) {
            unsigned int suf = sc[lv * 1024 + t];
            unsigned int excl = suf - s4[lv];
            if (excl < K && suf >= K) {         // unique crossing owner
                const unsigned int* h = hist + (size_t)lv * NB20;
                unsigned int cum = excl;
                for (int i = BPT - 1; i >= 0; --i) {
                    unsigned int c = ald(&h[(i << 10) | t]);
                    if (cum + c >= K) {
                        params[lv] = (unsigned int)(t * BPT + i);
                        params[8 + lv] = K - cum;
                        params[16 + lv] = 0;
                        break;
                    }
                    cum += c;
                }
            }
        } else if (t == 0) {
            params[lv] = 0; params[8 + lv] = 0; params[16 + lv] = K - tot;
        }
    }
    // ---- invOff scan (was k2 block-5); reuse sc[0..2047] ----
    __syncthreads();
    if (t < 512) {
        unsigned int vv = (t < NBLK) ? ald(&invBlk[t]) : 0u;
        sc[t] = vv; sc[1024 + t] = vv;
    }
    __syncthreads();
    for (int off = 1; off < 512; off <<= 1) {
        unsigned int add = 0;
        if (t < 512 && t >= off) add = sc[t - off];
        __syncthreads();
        if (t < 512) sc[t] += add;
        __syncthreads();
    }
    if (t < NBLK) {
        int segStart = (t < 256) ? 0 : (t < 320) ? 256 : (t < 336) ? 320
                     : (t < 340) ? 336 : 340;
        invOff[t] = sc[t] - sc[1024 + t] - (segStart > 0 ? sc[segStart - 1] : 0u);
    }
}

// ---------------------------------------------------------------- K3 (+K5)
// compaction + election: rank 340 resolves boundary, ranks 273..339 are the
// 67 rank/gather blocks (flag-spin, validated R5; reads via ald64 only).
__global__ __launch_bounds__(256) void k3_rank(InPtrs P,
        const unsigned int* sbits, const unsigned int* clsv,
        const unsigned int* params, const unsigned int* invOff,
        unsigned long long* finKeys, unsigned int* ctrs, unsigned long long* bBuf,
        float4* sBox, float* sScore, unsigned int* sCV, float* sArea) {
    int blk = blockIdx.x;
    int t = threadIdx.x;
    int a = blk * 256 + t;
    int lev, idx; lvl_of(a, lev, idx);
    unsigned int sb = sbits[a];
    unsigned int cv = clsv[a];
    unsigned int bin = (sb >> 12) - BASE20;
    unsigned int Bs = params[lev];
    unsigned int rNeg = params[16 + lev];
    unsigned int valid = cv >> 31;
    int lane = t & 63, w = t >> 6;
    unsigned long long lt = (1ull << lane) - 1ull;
    __shared__ unsigned int wInv[4], wFin[4], wB[4];
    __shared__ unsigned int baseFin, baseB, myRank, posS;
    __shared__ union {
        unsigned long long kb[BCAP];                               // 4 KB
        struct { unsigned long long keys[NF]; unsigned int rnk[64]; } rk; // 34.3 KB
    } u;
    unsigned long long mInv = __ballot(valid == 0u);
    if (lane == 0) wInv[w] = (unsigned int)__popcll(mInv);
    __syncthreads();
    unsigned int invRank = invOff[blk] + (unsigned int)__popcll(mInv & lt);
    for (int i = 0; i < w; ++i) invRank += wInv[i];
    bool isFin, isB;
    if (valid) { isFin = (bin > Bs); isB = (bin == Bs); }
    else       { isFin = (rNeg > 0) && (invRank < rNeg); isB = false; }
    unsigned long long mFin = __ballot(isFin);
    unsigned long long mB   = __ballot(isB);
    if (lane == 0) { wFin[w] = (unsigned int)__popcll(mFin);
                     wB[w]   = (unsigned int)__popcll(mB); }
    __syncthreads();
    if (t == 0) {
        unsigned int tf = wFin[0] + wFin[1] + wFin[2] + wFin[3];
        unsigned int tb = wB[0] + wB[1] + wB[2] + wB[3];
        baseFin = tf ? atomicAdd(&ctrs[0], tf) : 0u;
        baseB   = tb ? atomicAdd(&ctrs[1 + lev], tb) : 0u;
    }
    __syncthreads();
    if (isFin || isB) {
        unsigned int composite = ((unsigned int)lev << 16) | (unsigned int)idx;
        unsigned int inv = (~composite) & 0x7FFFFu;
        unsigned int low = (inv << 13) | (valid << 7) | (cv & 0x7Fu);
        unsigned long long key = ((unsigned long long)sb << 32) | low;
        if (isFin) {
            unsigned int p = baseFin + (unsigned int)__popcll(mFin & lt);
            for (int i = 0; i < w; ++i) p += wFin[i];
            if (p < NF) ast64(&finKeys[p], key);
        } else {
            unsigned int p = baseB + (unsigned int)__popcll(mB & lt);
            for (int i = 0; i < w; ++i) p += wB[i];
            if (p < BCAP) ast64(&bBuf[(size_t)lev * BCAP + p], key);
        }
    }
    // ---- election ----
    __syncthreads();
    if (t == 0) {
        asm volatile("s_waitcnt vmcnt(0)" ::: "memory");
        myRank = __hip_atomic_fetch_add(&ctrs[8], 1u,
                     __ATOMIC_RELAXED, __HIP_MEMORY_SCOPE_AGENT);
    }
    __syncthreads();
    unsigned int rk_ = myRank;
    if (rk_ < (unsigned int)(NBLK - 1 - NRANK)) return;   // ranks 0..272 exit

    if (rk_ == (unsigned int)(NBLK - 1)) {
        // ---- boundary resolution (tail) ----
        unsigned int fc = ald(&ctrs[0]);
        if (fc > NF) fc = NF;
        if (t == 0) posS = fc;
        __syncthreads();
        for (int blev = 0; blev < 5; ++blev) {
            unsigned int bc = ald(&ctrs[1 + blev]);
            int n = (bc > BCAP) ? BCAP : (int)bc;
            int r = (int)params[8 + blev];
            if (r > n) r = n;
            if (r > 0) {
                for (int i = t; i < n; i += 256)
                    u.kb[i] = ald64(&bBuf[(size_t)blev * BCAP + i]);
                __syncthreads();
                for (int i = t; i < n; i += 256) {
                    unsigned long long my = u.kb[i];
                    unsigned int c = 0;
                    for (int j = 0; j < n; ++j) c += (u.kb[j] > my) ? 1u : 0u;
                    if (c < (unsigned int)r) {
                        unsigned int p = atomicAdd(&posS, 1u);
                        if (p < NF) ast64(&finKeys[p], my);
                    }
                }
                __syncthreads();
            }
        }
        __syncthreads();
        for (int i = (int)posS + t; i < NF; i += 256)   // defensive
            ast64(&finKeys[i], (unsigned long long)i);
        __syncthreads();
        if (t == 0) {
            asm volatile("s_waitcnt vmcnt(0)" ::: "memory");
            ast(&ctrs[10], 1u);                 // release rank-blocks
        }
        return;
    }

    // ---- rank-block (was k5): guarded flag-spin, then rank 64 finalists ----
    if (t == 0) {
        int g = 0;
        while (ald(&ctrs[10]) == 0u && g < 200000) { __builtin_amdgcn_s_sleep(8); ++g; }
    }
    __syncthreads();
    int rb = (int)rk_ - (NBLK - 1 - NRANK);             // 0..66
    for (int i = t; i < NF; i += 256) u.rk.keys[i] = ald64(&finKeys[i]);
    if (t < 64) u.rk.rnk[t] = 0;
    __syncthreads();
    int lf = t & 63;
    int seg = t >> 6;                                   // 4 segments of 1064
    int f = rb * 64 + lf;
    unsigned long long my = (f < NF) ? u.rk.keys[f] : 0ull;
    if (f < NF) {
        unsigned int c = 0;
        const unsigned long long* kp = u.rk.keys + seg * 1064;
        #pragma unroll 8
        for (int i = 0; i < 1064; ++i) c += (kp[i] > my) ? 1u : 0u;
        atomicAdd(&u.rk.rnk[lf], c);
    }
    __syncthreads();
    if (seg == 0 && f < NF) {
        unsigned int r = u.rk.rnk[lf];
        unsigned int sbv = (unsigned int)(my >> 32);
        unsigned int low = (unsigned int)my;
        unsigned int composite = (~(low >> 13)) & 0x7FFFFu;
        int lev2 = composite >> 16;
        int idx2 = composite & 0xFFFF;
        float4 b = ((const float4*)P.reg[lev2])[idx2];
        float vy1 = P.loc[0], vx1 = P.loc[1], vy2 = P.loc[2], vx2 = P.loc[3];
        float y1 = fmaxf(b.x, vy1), x1 = fmaxf(b.y, vx1);
        float y2 = fminf(b.z, vy2), x2 = fminf(b.w, vx2);
        float area = __fmul_rn(fmaxf(y2 - y1, 0.0f), fmaxf(x2 - x1, 0.0f));
        unsigned int valid2 = (low >> 7) & 1u;
        sBox[r] = make_float4(y1, x1, y2, x2);          // plain: next kernel
        sScore[r] = valid2 ? funkey(sbv) : 0.0f;
        sCV[r] = (low & 0x7Fu) | (valid2 << 31);
        sArea[r] = area;
    }
}

// ---------------------------------------------------------------- K6
__global__ __launch_bounds__(256) void k6_adj(const float4* sBox,
        const float* sArea, unsigned int* cnt, unsigned short* nbr) {
    int L = blockIdx.x;
    float fr = sqrtf(8.0f * (float)L + 1.0f);
    int jt = (int)((fr - 1.0f) * 0.5f);
    while ((jt + 1) * (jt + 2) / 2 <= L) jt++;
    while (jt * (jt + 1) / 2 > L) jt--;
    int it = L - jt * (jt + 1) / 2;
    __shared__ float4 cb[64]; __shared__ float ca[64];
    __shared__ float4 rb[64]; __shared__ float ra[64];
    int t = threadIdx.x;
    if (t < 64) {
        int j = jt * 64 + t;
        if (j < NF) { cb[t] = sBox[j]; ca[t] = sArea[j]; }
        int i = it * 64 + t;
        if (i < NF) { rb[t] = sBox[i]; ra[t] = sArea[i]; }
    }
    __syncthreads();
    int lj = t & 63;
    int j = jt * 64 + lj;
    if (j >= NF) return;
    float4 B = cb[lj]; float ab = ca[lj];
    for (int li = (t >> 6); li < 64; li += 4) {
        int i = it * 64 + li;
        if (i >= j) continue;
        float4 A = rb[li]; float aa = ra[li];
        float iy1 = fmaxf(A.x, B.x), ix1 = fmaxf(A.y, B.y);
        float iy2 = fminf(A.z, B.z), ix2 = fminf(A.w, B.w);
        float ih = fmaxf(iy2 - iy1, 0.0f), iw = fmaxf(ix2 - ix1, 0.0f);
        float inter = __fmul_rn(ih, iw);
        float uni = __fsub_rn(__fadd_rn(aa, ab), inter);
        float iou = __fdiv_rn(inter, fmaxf(uni, 1e-9f));
        if (iou > 0.5f) {
            unsigned int p = atomicAdd(&cnt[j], 1u);
            if (p < CAPD) nbr[(size_t)j * CAPD + p] = (unsigned short)i;
        }
    }
}

// ---------------------------------------------------------------- K7
__global__ __launch_bounds__(1024) void k7_nms(InPtrs P, const float4* sBox,
        const float* sScore, const unsigned int* sCV, const unsigned int* cnt,
        const unsigned short* nbr, float* out) {
    __shared__ unsigned int edges[EC];
    __shared__ __align__(4) unsigned char bufA[NF];
    __shared__ __align__(4) unsigned char bufB[NF];
    __shared__ unsigned int wsum[16];
    __shared__ float ploc[6];
    __shared__ unsigned int chg;
    int t = threadIdx.x;
    int lane = t & 63, wid = t >> 6;
    if (t < 6) ploc[t] = P.loc[t];
    const int CH = 5;
    unsigned int dq[CH];
    unsigned int s = 0;
    #pragma unroll
    for (int q = 0; q < CH; ++q) {
        int j = t * CH + q;
        unsigned int d = 0;
        if (j < NF) { d = cnt[j]; if (d > CAPD) d = CAPD; }
        dq[q] = d; s += d;
    }
    unsigned int sc = s;
    #pragma unroll
    for (int o = 1; o < 64; o <<= 1) {
        unsigned int n = __shfl_up(sc, o, 64);
        if (lane >= o) sc += n;
    }
    if (lane == 63) wsum[wid] = sc;
    if (t < 1064) ((unsigned int*)bufA)[t] = 0x01010101u;   // NF=4256=1064*4
    __syncthreads();
    unsigned int wbase = 0, tot = 0;
    #pragma unroll
    for (int i = 0; i < 16; ++i) {
        unsigned int v = wsum[i];
        if (i < wid) wbase += v;
        tot += v;
    }
    unsigned int E = tot;
    bool useLds = (E <= (unsigned int)EC);
    if (useLds) {
        unsigned int base = wbase + sc - s;
        #pragma unroll
        for (int q = 0; q < CH; ++q) {
            int j = t * CH + q;
            if (j < NF) {
                unsigned int d = dq[q];
                const unsigned short* nl = nbr + (size_t)j * CAPD;
                for (unsigned int e = 0; e < d; ++e)
                    edges[base + e] = ((unsigned int)nl[e] << 16) | (unsigned int)j;
                base += d;
            }
        }
    }
    __syncthreads();
    unsigned char* cur = bufA; unsigned char* nxt = bufB;
    for (int itr = 0; itr < NITER; ++itr) {
        if (t < 1064) ((unsigned int*)nxt)[t] = 0x01010101u;
        __syncthreads();
        if (useLds) {
            for (int e = t; e < (int)E; e += 1024) {
                unsigned int pk = edges[e];
                if (cur[pk >> 16]) nxt[pk & 0xFFFFu] = 0;
            }
        } else {
            for (int j = t; j < NF; j += 1024) {
                unsigned int d = cnt[j]; if (d > CAPD) d = CAPD;
                const unsigned short* nl = nbr + (size_t)j * CAPD;
                unsigned int hit = 0;
                for (unsigned int e = 0; e < d; ++e)
                    hit |= (unsigned int)cur[nl[e]];
                if (hit) nxt[j] = 0;
            }
        }
        __syncthreads();
        if (t < 1064 &&
            ((unsigned int*)nxt)[t] != ((unsigned int*)cur)[t]) chg = 1;
        __syncthreads();
        unsigned int done = (chg == 0u);
        unsigned char* tm = cur; cur = nxt; nxt = tm;
        __syncthreads();
        if (t == 0) chg = 0;
        if (done) break;
    }
    // final keep & emit (wave-scan prefix)
    int base = t * CH;
    unsigned char kf[CH];
    unsigned int sum = 0;
    #pragma unroll
    for (int q = 0; q < CH; ++q) {
        int j = base + q;
        unsigned char v = 0;
        if (j < NF) v = cur[j] & (unsigned char)(sCV[j] >> 31);
        kf[q] = v; sum += v;
    }
    unsigned int sc2 = sum;
    #pragma unroll
    for (int o = 1; o < 64; o <<= 1) {
        unsigned int n = __shfl_up(sc2, o, 64);
        if (lane >= o) sc2 += n;
    }
    if (lane == 63) wsum[wid] = sc2;
    __syncthreads();
    unsigned int wbase2 = 0, keptTot = 0;
    #pragma unroll
    for (int i = 0; i < 16; ++i) {
        unsigned int v = wsum[i];
        if (i < wid) wbase2 += v;
        keptTot += v;
    }
    unsigned int run = wbase2 + sc2 - sum;
    float vy1 = ploc[0], vx1 = ploc[1], vy2 = ploc[2], vx2 = ploc[3];
    float sy = ploc[4] / fmaxf(vy2 - vy1, 1e-6f);
    float sx = ploc[5] / fmaxf(vx2 - vx1, 1e-6f);
    #pragma unroll
    for (int q = 0; q < CH; ++q) {
        int j = base + q;
        if (j >= NF) break;
        unsigned int slot = 0xFFFFFFFFu;
        float scv = 0.0f;
        if (kf[q]) {
            if (run < 100u) { slot = run; scv = sScore[j]; }
            run++;
        } else if (keptTot < 100u) {
            unsigned int nk = (unsigned int)j - run;
            unsigned int s2 = keptTot + nk;
            if (s2 < 100u) { slot = s2; scv = 0.0f; }
        }
        if (slot < 100u) {
            float4 b = sBox[j];
            out[slot * 4 + 0] = (b.x - vy1) * sy;
            out[slot * 4 + 1] = (b.y - vx1) * sx;
            out[slot * 4 + 2] = (b.z - vy1) * sy;
            out[slot * 4 + 3] = (b.w - vx1) * sx;
            out[400 + slot] = (float)(sCV[j] & 0x7Fu);
            out[500 + slot] = scv;
        }
    }
}

extern "C" void kernel_launch(void* const* d_in, const int* in_sizes, int n_in,
                              void* d_out, int out_size, void* d_ws, size_t ws_size,
                              hipStream_t stream) {
    (void)n_in; (void)out_size; (void)ws_size;
    InPtrs P;
    bool inter = (in_sizes[1] == 65536 * 4);
    for (int s = 0; s < 5; ++s) {
        P.cls[s] = (const float*)d_in[inter ? 2 * s : s];
        P.reg[s] = (const float*)d_in[inter ? 2 * s + 1 : 5 + s];
    }
    P.loc = (const float*)d_in[10];

    char* w = (char*)d_ws;
    unsigned int* hist   = (unsigned int*)(w + OFF_HIST);
    unsigned int* cnt    = (unsigned int*)(w + OFF_CNT);
    unsigned int* ctrs   = (unsigned int*)(w + OFF_CTR);
    unsigned int* sbits  = (unsigned int*)(w + OFF_SBITS);
    unsigned int* clsv   = (unsigned int*)(w + OFF_CLSV);
    unsigned int* params = (unsigned int*)(w + OFF_PAR);
    unsigned int* invBlk = (unsigned int*)(w + OFF_INVB);
    unsigned int* invOff = (unsigned int*)(w + OFF_INVO);
    unsigned long long* finKeys = (unsigned long long*)(w + OFF_FINK);
    unsigned long long* bBuf    = (unsigned long long*)(w + OFF_BBUF);
    float4* sBox  = (float4*)(w + OFF_SBOX);
    float* sScore = (float*)(w + OFF_SSC);
    unsigned int* sCV = (unsigned int*)(w + OFF_SCV);
    float* sArea  = (float*)(w + OFF_SAR);
    unsigned short* nbr = (unsigned short*)(w + OFF_NBR);

    hipMemsetAsync(d_ws, 0, ZERO_SZ, stream);
    k1_score<<<NBLK, 1024, 0, stream>>>(P, hist, sbits, clsv, invBlk,
                                        params, invOff, ctrs);
    k3_rank<<<NBLK, 256, 0, stream>>>(P, sbits, clsv, params, invOff,
                                      finKeys, ctrs, bBuf, sBox, sScore, sCV, sArea);
    k6_adj<<<2278, 256, 0, stream>>>(sBox, sArea, cnt, nbr);
    k7_nms<<<1, 1024, 0, stream>>>(P, sBox, sScore, sCV, cnt, nbr, (float*)d_out);
}

// Round 7
// 171.432 us; speedup vs baseline: 1.4304x; 1.1200x over previous
//
#include <hip/hip_runtime.h>
#include <math.h>

// Round-7: R4 structure (best measured, 173us; node overhead refit ~7us so
// R6's merges were net-negative -- reverted). Single change vs R4:
//   k1 __launch_bounds__(1024, 2): R6 counters showed k1 = 51us @ VALU 2.6%,
//   HBM 4%, VGPR_Count=24 -- the 5 in-flight float4 loads need ~28+ live
//   VGPRs, so at 24 the compiler serialized them into 2-3 waitcnt-separated
//   batches => latency-bound. Cap 128 (block-fit) lets all 5 loads fly.

#define NANCH 87296
#define NF 4256        // 1000*4 + 256 finalists
#define CAPD 128       // max neighbors per column
#define NITER 16       // 15 scan iterations + initial keep
#define BCAP 512       // boundary-bin buffer per level
#define EC 8192        // LDS edge cap (packed i<<16|j)
#define NBLK 341       // 256-anchor blocks; level boundaries are multiples of 256
#define BASE20 0xBD4CCu
#define NB20 9216      // padded to 1024 threads x 9 bins
#define BPT 9          // bins per k2 thread

struct InPtrs {
    const float* cls[5];
    const float* reg[5];
    const float* loc;
};

// workspace layout
constexpr size_t SZ_HIST  = 5ull * NB20 * 4;            // 184,320
constexpr size_t OFF_HIST = 0;
constexpr size_t OFF_CNT  = OFF_HIST + SZ_HIST;
constexpr size_t OFF_CTR  = OFF_CNT + (size_t)NF * 4;   // [0]=finCount,[1..5]=bCount,[8]=k3done
constexpr size_t ZERO_SZ  = OFF_CTR + 128;
constexpr size_t OFF_SBITS = ((ZERO_SZ + 255) / 256) * 256;
constexpr size_t OFF_CLSV  = OFF_SBITS + (size_t)NANCH * 4;
constexpr size_t OFF_PAR   = OFF_CLSV + (size_t)NANCH * 4;  // B*[5]@0,r*[5]@8,rNeg[5]@16
constexpr size_t OFF_INVB  = OFF_PAR + 128;
constexpr size_t OFF_INVO  = OFF_INVB + (size_t)NBLK * 4;
constexpr size_t OFF_FINK  = ((OFF_INVO + (size_t)NBLK * 4 + 255) / 256) * 256;
constexpr size_t OFF_BBUF  = OFF_FINK + (size_t)NF * 8;
constexpr size_t OFF_SBOX  = OFF_BBUF + 5ull * BCAP * 8;
constexpr size_t OFF_SSC   = OFF_SBOX + (size_t)NF * 16;
constexpr size_t OFF_SCV   = OFF_SSC + (size_t)NF * 4;
constexpr size_t OFF_SAR   = OFF_SCV + (size_t)NF * 4;
constexpr size_t OFF_NBR   = OFF_SAR + (size_t)NF * 4;

__device__ __forceinline__ void lvl_of(int a, int& lev, int& idx) {
    if (a < 65536)      { lev = 0; idx = a; }
    else if (a < 81920) { lev = 1; idx = a - 65536; }
    else if (a < 86016) { lev = 2; idx = a - 81920; }
    else if (a < 87040) { lev = 3; idx = a - 86016; }
    else                { lev = 4; idx = a - 87040; }
}

__device__ __forceinline__ unsigned int fkey(float f) {
    unsigned int u = __float_as_uint(f);
    return u ^ ((u & 0x80000000u) ? 0xFFFFFFFFu : 0x80000000u);
}
__device__ __forceinline__ float funkey(unsigned int k) {
    return __uint_as_float(k ^ ((k & 0x80000000u) ? 0x80000000u : 0xFFFFFFFFu));
}
__device__ __forceinline__ unsigned int bin20_addr(unsigned int v) {
    unsigned int owner = v / BPT;
    unsigned int i = v - owner * BPT;
    return (i << 10) | owner;
}
__device__ __forceinline__ unsigned int ald(const unsigned int* p) {
    return __hip_atomic_load((unsigned int*)p, __ATOMIC_RELAXED, __HIP_MEMORY_SCOPE_AGENT);
}
__device__ __forceinline__ void ast64(unsigned long long* p, unsigned long long v) {
    __hip_atomic_store(p, v, __ATOMIC_RELAXED, __HIP_MEMORY_SCOPE_AGENT);
}
__device__ __forceinline__ unsigned long long ald64(const unsigned long long* p) {
    return __hip_atomic_load((unsigned long long*)p, __ATOMIC_RELAXED, __HIP_MEMORY_SCOPE_AGENT);
}

// ---------------------------------------------------------------- K1
// launch_bounds(1024, 2): block-fit caps VGPR at 128 so all 5 float4 loads
// stay in flight (VGPR 24 in prior rounds serialized them -> 40-50us).
__global__ __launch_bounds__(1024, 2) void k1_score(InPtrs P, unsigned int* hist,
        unsigned int* sbits, unsigned int* clsv, unsigned int* invBlk) {
    int t = threadIdx.x;
    int a = blockIdx.x * 256 + (t >> 2);
    int k = t & 3;
    int lev, idx; lvl_of(a, lev, idx);
    const float4* row = (const float4*)(P.cls[lev] + (size_t)idx * 80);
    float4 v0 = row[0 * 4 + k];
    float4 v1 = row[1 * 4 + k];
    float4 v2 = row[2 * 4 + k];
    float4 v3 = row[3 * 4 + k];
    float4 v4 = row[4 * 4 + k];
    float best = -INFINITY; int bi = 0;
    float4 v[5] = { v0, v1, v2, v3, v4 };
    #pragma unroll
    for (int q = 0; q < 5; ++q) {
        int c0 = q * 16 + k * 4;
        if (v[q].x > best) { best = v[q].x; bi = c0 + 0; }
        if (v[q].y > best) { best = v[q].y; bi = c0 + 1; }
        if (v[q].z > best) { best = v[q].z; bi = c0 + 2; }
        if (v[q].w > best) { best = v[q].w; bi = c0 + 3; }
    }
    #pragma unroll
    for (int m = 1; m < 4; m <<= 1) {
        float ob = __shfl_xor(best, m, 64);
        int  obi = __shfl_xor(bi, m, 64);
        if (ob > best || (ob == best && obi < bi)) { best = ob; bi = obi; }
    }
    bool lead = (k == 0);
    unsigned int valid = 0;
    if (lead) {
        float score = 1.0f / (1.0f + expf(-best));
        valid = (score > 0.05f) ? 1u : 0u;
        float psm = valid ? score : -1.0f;
        unsigned int sb = fkey(psm);
        sbits[a] = sb;
        clsv[a] = (unsigned int)(bi + 1) | (valid << 31);
        if (valid) {
            unsigned int bin = (sb >> 12) - BASE20;   // in [0, 9012]
            atomicAdd(&hist[(size_t)lev * NB20 + bin20_addr(bin)], 1u);
        }
    }
    __shared__ unsigned int wv[16];
    unsigned long long mv = __ballot(lead && valid);
    int lane = t & 63, w = t >> 6;
    if (lane == 0) wv[w] = (unsigned int)__popcll(mv);
    __syncthreads();
    if (t == 0) {
        unsigned int s = 0;
        #pragma unroll
        for (int i = 0; i < 16; ++i) s += wv[i];
        invBlk[blockIdx.x] = 256u - s;
    }
}

// ---------------------------------------------------------------- K2
__global__ __launch_bounds__(1024) void k2_scan(const unsigned int* hist,
        const unsigned int* invBlk, unsigned int* params, unsigned int* invOff) {
    int t = threadIdx.x;
    if (blockIdx.x == 5) {
        __shared__ unsigned int sv[512];
        __shared__ unsigned int orig[512];
        if (t < 512) {
            unsigned int v = (t < NBLK) ? invBlk[t] : 0u;
            sv[t] = v; orig[t] = v;
        }
        __syncthreads();
        for (int off = 1; off < 512; off <<= 1) {
            unsigned int add = 0;
            if (t < 512 && t >= off) add = sv[t - off];
            __syncthreads();
            if (t < 512) sv[t] += add;
            __syncthreads();
        }
        if (t < NBLK) {
            int segStart = (t < 256) ? 0 : (t < 320) ? 256 : (t < 336) ? 320
                         : (t < 340) ? 336 : 340;
            invOff[t] = sv[t] - orig[t] - (segStart > 0 ? sv[segStart - 1] : 0u);
        }
        return;
    }
    int lev = blockIdx.x;
    unsigned int K = (lev == 4) ? 256u : 1000u;
    const unsigned int* h = hist + (size_t)lev * NB20;
    __shared__ unsigned int seg[1024];
    __shared__ unsigned int suf[1024];
    unsigned int hc[BPT];
    unsigned int s = 0;
    #pragma unroll
    for (int i = 0; i < BPT; ++i) { hc[i] = h[(i << 10) | t]; s += hc[i]; }
    seg[t] = s;
    suf[t] = s;
    __syncthreads();
    for (int off = 1; off < 1024; off <<= 1) {
        unsigned int v = suf[t];
        unsigned int add = (t + off < 1024) ? suf[t + off] : 0u;
        __syncthreads();
        suf[t] = v + add;
        __syncthreads();
    }
    unsigned int totValid = suf[0];
    if (totValid >= K) {
        unsigned int excl = suf[t] - seg[t];
        if (excl < K && excl + seg[t] >= K) {
            unsigned int cum = excl;
            for (int i = BPT - 1; i >= 0; --i) {
                unsigned int c = hc[i];
                if (cum + c >= K) {
                    params[lev] = (unsigned int)(t * BPT + i);
                    params[8 + lev] = K - cum;
                    params[16 + lev] = 0;
                    break;
                }
                cum += c;
            }
        }
    } else if (t == 0) {
        params[lev] = 0;              // all valid pass (valid bins > 0)
        params[8 + lev] = 0;
        params[16 + lev] = K - totValid;
    }
}

// ---------------------------------------------------------------- K3
// Compaction + tail-block boundary resolution (retire election, R4-validated).
__global__ __launch_bounds__(256) void k3_compact(const unsigned int* sbits,
        const unsigned int* clsv, const unsigned int* params,
        const unsigned int* invOff, unsigned long long* finKeys,
        unsigned int* ctrs, unsigned long long* bBuf) {
    int blk = blockIdx.x;
    int t = threadIdx.x;
    int a = blk * 256 + t;
    int lev, idx; lvl_of(a, lev, idx);
    unsigned int sb = sbits[a];
    unsigned int cv = clsv[a];
    unsigned int bin = (sb >> 12) - BASE20;   // meaningful for valid only
    unsigned int Bs = params[lev];
    unsigned int rNeg = params[16 + lev];
    unsigned int valid = cv >> 31;
    int lane = t & 63, w = t >> 6;
    unsigned long long lt = (1ull << lane) - 1ull;
    __shared__ unsigned int wInv[4], wFin[4], wB[4];
    __shared__ unsigned int baseFin, baseB;
    unsigned long long mInv = __ballot(valid == 0u);
    if (lane == 0) wInv[w] = (unsigned int)__popcll(mInv);
    __syncthreads();
    unsigned int invRank = invOff[blk] + (unsigned int)__popcll(mInv & lt);
    for (int i = 0; i < w; ++i) invRank += wInv[i];
    bool isFin, isB;
    if (valid) {
        isFin = (bin > Bs);
        isB   = (bin == Bs);
    } else {
        isFin = (rNeg > 0) && (invRank < rNeg);
        isB   = false;
    }
    unsigned long long mFin = __ballot(isFin);
    unsigned long long mB   = __ballot(isB);
    if (lane == 0) { wFin[w] = (unsigned int)__popcll(mFin); wB[w] = (unsigned int)__popcll(mB); }
    __syncthreads();
    if (t == 0) {
        unsigned int tf = wFin[0] + wFin[1] + wFin[2] + wFin[3];
        unsigned int tb = wB[0] + wB[1] + wB[2] + wB[3];
        baseFin = tf ? atomicAdd(&ctrs[0], tf) : 0u;
        baseB   = tb ? atomicAdd(&ctrs[1 + lev], tb) : 0u;
    }
    __syncthreads();
    if (isFin || isB) {
        unsigned int composite = ((unsigned int)lev << 16) | (unsigned int)idx;
        unsigned int inv = (~composite) & 0x7FFFFu;
        unsigned int low = (inv << 13) | (valid << 7) | (cv & 0x7Fu);
        unsigned long long key = ((unsigned long long)sb << 32) | low;
        if (isFin) {
            unsigned int p = baseFin + (unsigned int)__popcll(mFin & lt);
            for (int i = 0; i < w; ++i) p += wFin[i];
            if (p < NF) finKeys[p] = key;
        } else {
            unsigned int p = baseB + (unsigned int)__popcll(mB & lt);
            for (int i = 0; i < w; ++i) p += wB[i];
            if (p < BCAP) ast64(&bBuf[(size_t)lev * BCAP + p], key);
        }
    }
    // ---- tail election: last block resolves the boundary bins -------------
    __shared__ unsigned int isLast;
    __shared__ unsigned long long kb[BCAP];
    __shared__ unsigned int posS;
    __syncthreads();                // all waves' stores drained
    if (t == 0) {
        asm volatile("s_waitcnt vmcnt(0)" ::: "memory");
        unsigned int r = __hip_atomic_fetch_add(&ctrs[8], 1u,
                             __ATOMIC_RELAXED, __HIP_MEMORY_SCOPE_AGENT);
        isLast = (r == (unsigned int)(NBLK - 1)) ? 1u : 0u;
    }
    __syncthreads();
    if (!isLast) return;
    unsigned int fc = ald(&ctrs[0]);
    if (fc > NF) fc = NF;
    if (t == 0) posS = fc;
    __syncthreads();
    for (int blev = 0; blev < 5; ++blev) {
        unsigned int bc = ald(&ctrs[1 + blev]);
        int n = (bc > BCAP) ? BCAP : (int)bc;
        int r = (int)params[8 + blev];
        if (r > n) r = n;
        if (r > 0) {
            for (int i = t; i < n; i += 256)
                kb[i] = ald64(&bBuf[(size_t)blev * BCAP + i]);
            __syncthreads();
            for (int i = t; i < n; i += 256) {
                unsigned long long my = kb[i];
                unsigned int c = 0;
                for (int j = 0; j < n; ++j) c += (kb[j] > my) ? 1u : 0u;
                if (c < (unsigned int)r) {
                    unsigned int p = atomicAdd(&posS, 1u);
                    if (p < NF) finKeys[p] = my;
                }
            }
            __syncthreads();
        }
    }
    for (int i = (int)posS + t; i < NF; i += 256)   // defensive (posS==NF normally)
        finKeys[i] = (unsigned long long)i;
}

// ---------------------------------------------------------------- K5
// Pure rank + gather: 67 blocks x 1024 threads, 64 finalists per block.
__global__ __launch_bounds__(1024) void k5_rank(InPtrs P,
        const unsigned long long* finKeys,
        float4* sBox, float* sScore, unsigned int* sCV, float* sArea) {
    __shared__ __align__(16) unsigned long long keys[NF];
    __shared__ unsigned int rnk[64];
    int t = threadIdx.x;
    {   // vectorized key load (NF = 2128 ulonglong2)
        const ulonglong2* src = (const ulonglong2*)finKeys;
        ulonglong2* dst = (ulonglong2*)keys;
        for (int i = t; i < NF / 2; i += 1024) dst[i] = src[i];
    }
    if (t < 64) rnk[t] = 0;
    __syncthreads();
    int lf = t & 63;
    int seg = t >> 6;                       // 16 segments of 266 keys
    int f = blockIdx.x * 64 + lf;
    unsigned long long my = (f < NF) ? keys[f] : 0ull;
    if (f < NF) {
        unsigned int c = 0;
        const ulonglong2* kp = (const ulonglong2*)keys + seg * 133;
        #pragma unroll 4
        for (int i = 0; i < 133; ++i) {
            ulonglong2 v = kp[i];
            c += (v.x > my) ? 1u : 0u;
            c += (v.y > my) ? 1u : 0u;
        }
        atomicAdd(&rnk[lf], c);
    }
    __syncthreads();
    if (seg == 0 && f < NF) {
        unsigned int r = rnk[lf];
        unsigned int sb  = (unsigned int)(my >> 32);
        unsigned int low = (unsigned int)my;
        unsigned int composite = (~(low >> 13)) & 0x7FFFFu;
        int lev = composite >> 16;
        int idx = composite & 0xFFFF;
        float4 b = ((const float4*)P.reg[lev])[idx];
        float vy1 = P.loc[0], vx1 = P.loc[1], vy2 = P.loc[2], vx2 = P.loc[3];
        float y1 = fmaxf(b.x, vy1), x1 = fmaxf(b.y, vx1);
        float y2 = fminf(b.z, vy2), x2 = fminf(b.w, vx2);
        float area = __fmul_rn(fmaxf(y2 - y1, 0.0f), fmaxf(x2 - x1, 0.0f));
        unsigned int valid = (low >> 7) & 1u;
        sBox[r] = make_float4(y1, x1, y2, x2);
        sScore[r] = valid ? funkey(sb) : 0.0f;
        sCV[r] = (low & 0x7Fu) | (valid << 31);
        sArea[r] = area;
    }
}

// ---------------------------------------------------------------- K6
__global__ __launch_bounds__(256) void k6_adj(const float4* sBox,
        const float* sArea, unsigned int* cnt, unsigned short* nbr) {
    int L = blockIdx.x;
    float fr = sqrtf(8.0f * (float)L + 1.0f);
    int jt = (int)((fr - 1.0f) * 0.5f);
    while ((jt + 1) * (jt + 2) / 2 <= L) jt++;
    while (jt * (jt + 1) / 2 > L) jt--;
    int it = L - jt * (jt + 1) / 2;
    __shared__ float4 cb[64]; __shared__ float ca[64];
    __shared__ float4 rb[64]; __shared__ float ra[64];
    int t = threadIdx.x;
    if (t < 64) {
        int j = jt * 64 + t;
        if (j < NF) { cb[t] = sBox[j]; ca[t] = sArea[j]; }
        int i = it * 64 + t;
        if (i < NF) { rb[t] = sBox[i]; ra[t] = sArea[i]; }
    }
    __syncthreads();
    int lj = t & 63;
    int j = jt * 64 + lj;
    if (j >= NF) return;
    float4 B = cb[lj]; float ab = ca[lj];
    for (int li = (t >> 6); li < 64; li += 4) {
        int i = it * 64 + li;
        if (i >= j) continue;
        float4 A = rb[li]; float aa = ra[li];
        float iy1 = fmaxf(A.x, B.x), ix1 = fmaxf(A.y, B.y);
        float iy2 = fminf(A.z, B.z), ix2 = fminf(A.w, B.w);
        float ih = fmaxf(iy2 - iy1, 0.0f), iw = fmaxf(ix2 - ix1, 0.0f);
        float inter = __fmul_rn(ih, iw);
        float uni = __fsub_rn(__fadd_rn(aa, ab), inter);
        float iou = __fdiv_rn(inter, fmaxf(uni, 1e-9f));
        if (iou > 0.5f) {
            unsigned int p = atomicAdd(&cnt[j], 1u);
            if (p < CAPD) nbr[(size_t)j * CAPD + p] = (unsigned short)i;
        }
    }
}

// ---------------------------------------------------------------- K7
// Edge-parallel NMS with convergence early-exit.
__global__ __launch_bounds__(1024) void k7_nms(InPtrs P, const float4* sBox,
        const float* sScore, const unsigned int* sCV, const unsigned int* cnt,
        const unsigned short* nbr, float* out) {
    __shared__ unsigned int edges[EC];
    __shared__ __align__(4) unsigned char bufA[NF];
    __shared__ __align__(4) unsigned char bufB[NF];
    __shared__ unsigned int wsum[16];
    __shared__ float ploc[6];
    __shared__ unsigned int chg;
    int t = threadIdx.x;
    int lane = t & 63, wid = t >> 6;
    if (t < 6) ploc[t] = P.loc[t];
    const int CH = 5;
    unsigned int dq[CH];
    unsigned int s = 0;
    #pragma unroll
    for (int q = 0; q < CH; ++q) {
        int j = t * CH + q;
        unsigned int d = 0;
        if (j < NF) { d = cnt[j]; if (d > CAPD) d = CAPD; }
        dq[q] = d; s += d;
    }
    unsigned int sc = s;
    #pragma unroll
    for (int o = 1; o < 64; o <<= 1) {
        unsigned int n = __shfl_up(sc, o, 64);
        if (lane >= o) sc += n;
    }
    if (lane == 63) wsum[wid] = sc;
    if (t < 1064) ((unsigned int*)bufA)[t] = 0x01010101u;   // NF=4256=1064*4
    __syncthreads();
    unsigned int wbase = 0, tot = 0;
    #pragma unroll
    for (int i = 0; i < 16; ++i) {
        unsigned int v = wsum[i];
        if (i < wid) wbase += v;
        tot += v;
    }
    unsigned int E = tot;
    bool useLds = (E <= (unsigned int)EC);
    if (useLds) {
        unsigned int base = wbase + sc - s;   // exclusive prefix
        #pragma unroll
        for (int q = 0; q < CH; ++q) {
            int j = t * CH + q;
            if (j < NF) {
                unsigned int d = dq[q];
                const unsigned short* nl = nbr + (size_t)j * CAPD;
                for (unsigned int e = 0; e < d; ++e)
                    edges[base + e] = ((unsigned int)nl[e] << 16) | (unsigned int)j;
                base += d;
            }
        }
    }
    __syncthreads();
    unsigned char* cur = bufA; unsigned char* nxt = bufB;
    for (int itr = 0; itr < NITER; ++itr) {
        if (t < 1064) ((unsigned int*)nxt)[t] = 0x01010101u;
        __syncthreads();
        if (useLds) {
            for (int e = t; e < (int)E; e += 1024) {
                unsigned int pk = edges[e];
                if (cur[pk >> 16]) nxt[pk & 0xFFFFu] = 0;
            }
        } else {
            for (int j = t; j < NF; j += 1024) {
                unsigned int d = cnt[j]; if (d > CAPD) d = CAPD;
                const unsigned short* nl = nbr + (size_t)j * CAPD;
                unsigned int hit = 0;
                for (unsigned int e = 0; e < d; ++e)
                    hit |= (unsigned int)cur[nl[e]];
                if (hit) nxt[j] = 0;
            }
        }
        __syncthreads();
        if (t < 1064 &&
            ((unsigned int*)nxt)[t] != ((unsigned int*)cur)[t]) chg = 1;
        __syncthreads();
        unsigned int done = (chg == 0u);
        unsigned char* tm = cur; cur = nxt; nxt = tm;
        __syncthreads();
        if (t == 0) chg = 0;
        if (done) break;
    }
    // final keep & emit (wave-scan prefix)
    int base = t * CH;
    unsigned char kf[CH];
    unsigned int sum = 0;
    #pragma unroll
    for (int q = 0; q < CH; ++q) {
        int j = base + q;
        unsigned char v = 0;
        if (j < NF) v = cur[j] & (unsigned char)(sCV[j] >> 31);
        kf[q] = v; sum += v;
    }
    unsigned int sc2 = sum;
    #pragma unroll
    for (int o = 1; o < 64; o <<= 1) {
        unsigned int n = __shfl_up(sc2, o, 64);
        if (lane >= o) sc2 += n;
    }
    if (lane == 63) wsum[wid] = sc2;
    __syncthreads();
    unsigned int wbase2 = 0, keptTot = 0;
    #pragma unroll
    for (int i = 0; i < 16; ++i) {
        unsigned int v = wsum[i];
        if (i < wid) wbase2 += v;
        keptTot += v;
    }
    unsigned int run = wbase2 + sc2 - sum;
    float vy1 = ploc[0], vx1 = ploc[1], vy2 = ploc[2], vx2 = ploc[3];
    float sy = ploc[4] / fmaxf(vy2 - vy1, 1e-6f);
    float sx = ploc[5] / fmaxf(vx2 - vx1, 1e-6f);
    #pragma unroll
    for (int q = 0; q < CH; ++q) {
        int j = base + q;
        if (j >= NF) break;
        unsigned int slot = 0xFFFFFFFFu;
        float scv = 0.0f;
        if (kf[q]) {
            if (run < 100u) { slot = run; scv = sScore[j]; }
            run++;
        } else if (keptTot < 100u) {
            unsigned int nk = (unsigned int)j - run;
            unsigned int s2 = keptTot + nk;
            if (s2 < 100u) { slot = s2; scv = 0.0f; }
        }
        if (slot < 100u) {
            float4 b = sBox[j];
            out[slot * 4 + 0] = (b.x - vy1) * sy;
            out[slot * 4 + 1] = (b.y - vx1) * sx;
            out[slot * 4 + 2] = (b.z - vy1) * sy;
            out[slot * 4 + 3] = (b.w - vx1) * sx;
            out[400 + slot] = (float)(sCV[j] & 0x7Fu);
            out[500 + slot] = scv;
        }
    }
}

extern "C" void kernel_launch(void* const* d_in, const int* in_sizes, int n_in,
                              void* d_out, int out_size, void* d_ws, size_t ws_size,
                              hipStream_t stream) {
    (void)n_in; (void)out_size; (void)ws_size;
    InPtrs P;
    bool inter = (in_sizes[1] == 65536 * 4);
    for (int s = 0; s < 5; ++s) {
        P.cls[s] = (const float*)d_in[inter ? 2 * s : s];
        P.reg[s] = (const float*)d_in[inter ? 2 * s + 1 : 5 + s];
    }
    P.loc = (const float*)d_in[10];

    char* w = (char*)d_ws;
    unsigned int* hist   = (unsigned int*)(w + OFF_HIST);
    unsigned int* cnt    = (unsigned int*)(w + OFF_CNT);
    unsigned int* ctrs   = (unsigned int*)(w + OFF_CTR);
    unsigned int* sbits  = (unsigned int*)(w + OFF_SBITS);
    unsigned int* clsv   = (unsigned int*)(w + OFF_CLSV);
    unsigned int* params = (unsigned int*)(w + OFF_PAR);
    unsigned int* invBlk = (unsigned int*)(w + OFF_INVB);
    unsigned int* invOff = (unsigned int*)(w + OFF_INVO);
    unsigned long long* finKeys = (unsigned long long*)(w + OFF_FINK);
    unsigned long long* bBuf    = (unsigned long long*)(w + OFF_BBUF);
    float4* sBox  = (float4*)(w + OFF_SBOX);
    float* sScore = (float*)(w + OFF_SSC);
    unsigned int* sCV = (unsigned int*)(w + OFF_SCV);
    float* sArea  = (float*)(w + OFF_SAR);
    unsigned short* nbr = (unsigned short*)(w + OFF_NBR);

    hipMemsetAsync(d_ws, 0, ZERO_SZ, stream);
    k1_score<<<NBLK, 1024, 0, stream>>>(P, hist, sbits, clsv, invBlk);
    k2_scan<<<6, 1024, 0, stream>>>(hist, invBlk, params, invOff);
    k3_compact<<<NBLK, 256, 0, stream>>>(sbits, clsv, params, invOff, finKeys, ctrs, bBuf);
    k5_rank<<<67, 1024, 0, stream>>>(P, finKeys, sBox, sScore, sCV, sArea);
    k6_adj<<<2278, 256, 0, stream>>>(sBox, sArea, cnt, nbr);
    k7_nms<<<1, 1024, 0, stream>>>(P, sBox, sScore, sCV, cnt, nbr, (float*)d_out);
}